// Round 15
// baseline (190.097 us; speedup 1.0000x reference)
//
#include <hip/hip_runtime.h>
#include <stdint.h>

typedef __attribute__((ext_vector_type(4))) float f32x4;
typedef unsigned long long u64;
typedef __attribute__((ext_vector_type(2))) u64 u64x2;

#define CC   192
#define NN   16384
#define EE   4
#define HIDD 384

// LDS map (static, 78640 B -> 2 blocks/CU at 160K):
//  [0,     12800)  X tile [64 tok][200B] fp8 — resident whole kernel
//  [12800, 25600)  hid [64 slot][200B] fp8, SINGLE buffer (partials pre-loop)
//  [25600, 76560)  out accumulator f32 [65 rows][784B] (row 64 = pad dump)
//  [76560, 77584)  gates [64 tok][4 e] f32
//  [77584, 78608)  lists u32 [4 e][64 slot] (compacted token ids; pads = 0)
//  [78608, 78640)  ng[4] (group counts) @ +0, cnt[4] (token counts) @ +16
// Round 15: top-2 token compaction. Router wave builds per-expert lists via
// ballot/popc; G1 gathers X by token id; hid/G2 run in compacted slot space;
// G2 scatter-adds into LDS out (b128 RMW; pads scatter to dump row 64 with
// gate forced 0 -> no lost-update race). Weight-prefetch pipeline (21 loads
// in flight, counted vmcnt, raw barriers) is R13/R14's, unchanged.
#define OFF_X    0u
#define OFF_HID  12800u
#define OFF_PART 12800u
#define OFF_OUT  25600u
#define OFF_GATE 76560u
#define OFF_LIST 77584u
#define OFF_CNT  78608u
#define LDS_SZ   78640
#define XROWB    200u
#define OROWB    784u

// ---- fp8 e4m3fn convert
__device__ __forceinline__ uint32_t fp8b(float f){
  uint32_t u = __builtin_bit_cast(uint32_t, f);
  uint32_t s = (u >> 24) & 0x80u;
  float af = fminf(__builtin_fabsf(f), 448.0f);
  if (af < 0.015625f) return s;
  uint32_t v = __builtin_bit_cast(uint32_t, af);
  v += 0x7FFFFu + ((v >> 20) & 1u);
  uint32_t e = (v >> 23) - 120u;
  return s | (e << 3) | ((v >> 20) & 7u);
}
#if __has_builtin(__builtin_amdgcn_cvt_pk_fp8_f32)
__device__ __forceinline__ uint32_t fp8x4(float a, float b, float c, float d){
  int v = __builtin_amdgcn_cvt_pk_fp8_f32(a, b, 0, false);
  v = __builtin_amdgcn_cvt_pk_fp8_f32(c, d, v, true);
  return (uint32_t)v;
}
#else
__device__ __forceinline__ uint32_t fp8x4(float a, float b, float c, float d){
  return fp8b(a) | (fp8b(b) << 8) | (fp8b(c) << 16) | (fp8b(d) << 24);
}
#endif
// sigmoid-form GELU (R14-proven: absmax 0.046875)
__device__ __forceinline__ float gelu_f(float v){
  float e = __builtin_amdgcn_exp2f(v * -2.4554669f);
  return v * __builtin_amdgcn_rcpf(1.0f + e);
}
__device__ __forceinline__ f32x4 mfma8(u64 a, u64 b, f32x4 c){
  asm("v_mfma_f32_16x16x32_fp8_fp8 %0, %1, %2, %0" : "+v"(c) : "v"(a), "v"(b));
  return c;
}

#define WAITV(n) do{ asm volatile("s_waitcnt vmcnt(" #n ")"); \
                     __builtin_amdgcn_sched_barrier(0); }while(0)
#define BARRIER() do{ __builtin_amdgcn_sched_barrier(0); \
                      asm volatile("s_waitcnt lgkmcnt(0)"); \
                      __builtin_amdgcn_s_barrier(); \
                      __builtin_amdgcn_sched_barrier(0); }while(0)

// issue-only: 9 weight dwordx4 + 3 bias f32x4 (12 in flight)
__device__ __forceinline__ void issue_w1(const uint8_t* a0, const uint8_t* a1,
                                         const uint8_t* a2, const float* bb,
                                         u64x2 (&w)[9], f32x4 (&bv)[3]){
  asm volatile(
    "global_load_dwordx4 %0, %[A0], off\n\t"
    "global_load_dwordx4 %1, %[A0], off offset:16\n\t"
    "global_load_dwordx4 %2, %[A0], off offset:32\n\t"
    "global_load_dwordx4 %3, %[A1], off\n\t"
    "global_load_dwordx4 %4, %[A1], off offset:16\n\t"
    "global_load_dwordx4 %5, %[A1], off offset:32\n\t"
    "global_load_dwordx4 %6, %[A2], off\n\t"
    "global_load_dwordx4 %7, %[A2], off offset:16\n\t"
    "global_load_dwordx4 %8, %[A2], off offset:32\n\t"
    "global_load_dwordx4 %9, %[B], off\n\t"
    "global_load_dwordx4 %10, %[B], off offset:64\n\t"
    "global_load_dwordx4 %11, %[B], off offset:128"
    : "=&v"(w[0]), "=&v"(w[1]), "=&v"(w[2]), "=&v"(w[3]), "=&v"(w[4]), "=&v"(w[5]),
      "=&v"(w[6]), "=&v"(w[7]), "=&v"(w[8]), "=&v"(bv[0]), "=&v"(bv[1]), "=&v"(bv[2])
    : [A0]"v"(a0), [A1]"v"(a1), [A2]"v"(a2), [B]"v"(bb));
}
__device__ __forceinline__ void issue_w2(const uint8_t* a0, const uint8_t* a1,
                                         const uint8_t* a2, u64x2 (&w)[9]){
  asm volatile(
    "global_load_dwordx4 %0, %[A0], off\n\t"
    "global_load_dwordx4 %1, %[A0], off offset:16\n\t"
    "global_load_dwordx4 %2, %[A0], off offset:32\n\t"
    "global_load_dwordx4 %3, %[A1], off\n\t"
    "global_load_dwordx4 %4, %[A1], off offset:16\n\t"
    "global_load_dwordx4 %5, %[A1], off offset:32\n\t"
    "global_load_dwordx4 %6, %[A2], off\n\t"
    "global_load_dwordx4 %7, %[A2], off offset:16\n\t"
    "global_load_dwordx4 %8, %[A2], off offset:32"
    : "=&v"(w[0]), "=&v"(w[1]), "=&v"(w[2]), "=&v"(w[3]), "=&v"(w[4]), "=&v"(w[5]),
      "=&v"(w[6]), "=&v"(w[7]), "=&v"(w[8])
    : [A0]"v"(a0), [A1]"v"(a1), [A2]"v"(a2));
}

// weight convert + permute (unchanged from R13/R14)
extern "C" __global__ void kconv(const float* __restrict__ w1, const float* __restrict__ w2,
                                 uint8_t* __restrict__ w1f8, uint8_t* __restrict__ w2f8){
  int i = blockIdx.x * 256 + threadIdx.x;
  {
    int row = i / 192, k = i % 192;
    int o = k >> 3, kk = o >> 2, lg = o & 3, bi = k & 7;
    w1f8[(size_t)row * 192 + lg * 48 + kk * 8 + bi] = (uint8_t)fp8b(w1[i]);
  }
  {
    int row = i / 384, k = i % 384;
    int o = k >> 3, kk = o >> 2, lg = o & 3, bi = k & 7;
    w2f8[(size_t)row * 384 + lg * 96 + kk * 8 + bi] = (uint8_t)fp8b(w2[i]);
  }
}

__global__ __launch_bounds__(256)
__attribute__((amdgpu_waves_per_eu(2, 2)))
void kmoe(const float* __restrict__ x, const float* __restrict__ rw,
          const float* __restrict__ rb, const uint8_t* __restrict__ w1f8,
          const float* __restrict__ b1, const uint8_t* __restrict__ w2f8,
          const float* __restrict__ b2, const float* __restrict__ scp,
          float* __restrict__ out)
{
  __shared__ __align__(16) unsigned char S[LDS_SZ];
  const int tid  = threadIdx.x;
  const int lane = tid & 63;
  const int wv   = tid >> 6;
  const int lq   = lane & 15;
  const int lg   = lane >> 4;
  const int tile = blockIdx.x;
  const int b    = tile >> 8;
  const int n0   = (tile & 255) << 6;
  const float* xb = x + (size_t)b * CC * NN;

  // ---- stage X (fp8, stride-200 rows) + fp32 router partials
  {
    const int t = lane;
    const uint32_t rowbase = (uint32_t)t * XROWB;
    float a0 = 0.f, a1 = 0.f, a2 = 0.f, a3 = 0.f;
    #pragma unroll
    for (int jj = 0; jj < 6; ++jj){
      float v[8];
      #pragma unroll
      for (int j = 0; j < 8; ++j){
        const int c = wv * 48 + jj * 8 + j;
        v[j] = xb[(size_t)c * NN + n0 + t];
        a0 = __builtin_fmaf(v[j], rw[c],          a0);
        a1 = __builtin_fmaf(v[j], rw[CC + c],     a1);
        a2 = __builtin_fmaf(v[j], rw[2 * CC + c], a2);
        a3 = __builtin_fmaf(v[j], rw[3 * CC + c], a3);
      }
      uint2 p;
      p.x = fp8x4(v[0], v[1], v[2], v[3]);
      p.y = fp8x4(v[4], v[5], v[6], v[7]);
      *(uint2*)(S + rowbase + (uint32_t)(wv * 48 + jj * 8)) = p;
    }
    float* pl = (float*)(S + OFF_PART);
    pl[(wv * 4 + 0) * 64 + t] = a0;
    pl[(wv * 4 + 1) * 64 + t] = a1;
    pl[(wv * 4 + 2) * 64 + t] = a2;
    pl[(wv * 4 + 3) * 64 + t] = a3;
  }
  __syncthreads();

  // ---- router finalize + COMPACTION (wave 0 only = tid<64)
  if (tid < 64){
    const int t = tid;
    const float* pl = (const float*)(S + OFF_PART);
    float l0 = rb[0], l1 = rb[1], l2 = rb[2], l3 = rb[3];
    #pragma unroll
    for (int cg = 0; cg < 4; ++cg){
      l0 += pl[(cg * 4 + 0) * 64 + t];
      l1 += pl[(cg * 4 + 1) * 64 + t];
      l2 += pl[(cg * 4 + 2) * 64 + t];
      l3 += pl[(cg * 4 + 3) * 64 + t];
    }
    int i1 = 0; float v1 = l0;
    if (l1 > v1){ v1 = l1; i1 = 1; }
    if (l2 > v1){ v1 = l2; i1 = 2; }
    if (l3 > v1){ v1 = l3; i1 = 3; }
    float v2 = -3.0e38f; int i2 = 0;
    if (i1 != 0){ v2 = l0; i2 = 0; }
    if (i1 != 1 && l1 > v2){ v2 = l1; i2 = 1; }
    if (i1 != 2 && l2 > v2){ v2 = l2; i2 = 2; }
    if (i1 != 3 && l3 > v2){ v2 = l3; i2 = 3; }
    const float ex = __expf(v2 - v1);
    const float ga = 1.0f / (1.0f + ex);
    const float gb = ex * ga;
    float* glw = (float*)(S + OFF_GATE);
    glw[t * 4 + 0] = (i1 == 0) ? ga : ((i2 == 0) ? gb : 0.0f);
    glw[t * 4 + 1] = (i1 == 1) ? ga : ((i2 == 1) ? gb : 0.0f);
    glw[t * 4 + 2] = (i1 == 2) ? ga : ((i2 == 2) ? gb : 0.0f);
    glw[t * 4 + 3] = (i1 == 3) ? ga : ((i2 == 3) ? gb : 0.0f);
    // per-expert compacted token lists (ballot within wave 0)
    uint32_t* lst = (uint32_t*)(S + OFF_LIST);
    uint32_t* cw  = (uint32_t*)(S + OFF_CNT);
    #pragma unroll
    for (int e = 0; e < 4; ++e){
      const bool mine = (i1 == e) || (i2 == e);
      const u64 msk = __ballot(mine);
      const int cnt = __popcll(msk);
      const int ng  = (cnt + 15) >> 4;
      if (mine){
        const int slot = (int)__popcll(msk & ((1ull << t) - 1ull));
        lst[e * 64 + slot] = (uint32_t)t;
      }
      if (t >= cnt && t < ng * 16) lst[e * 64 + t] = 0u;   // pad: gather row 0
      if (t == 0){ cw[e] = (uint32_t)ng; cw[4 + e] = (uint32_t)cnt; }
    }
  }
  __syncthreads();   // X, gates, lists, counts settled

  const float* gl = (const float*)(S + OFF_GATE);
  const uint32_t* lst = (const uint32_t*)(S + OFF_LIST);
  const int* cw = (const int*)(S + OFF_CNT);
  uint32_t rowh[4];
  #pragma unroll
  for (int np = 0; np < 4; ++np) rowh[np] = OFF_HID + (uint32_t)(16 * np + lq) * XROWB;

  const uint8_t* w1l = w1f8 + (size_t)(wv * 48 + lq) * 192 + lg * 48;
  const uint8_t* w2l = w2f8 + (size_t)(wv * 48 + lq) * 384 + lg * 96;
  const float*   b1l = b1 + wv * 48 + 4 * lg;

  u64x2 W1[9], W2[9];
  f32x4 BV[3];
  f32x4 oacc[3][4];
  #pragma unroll
  for (int m = 0; m < 3; ++m)
    #pragma unroll
    for (int np = 0; np < 4; ++np)
      oacc[m][np] = (f32x4){0.f, 0.f, 0.f, 0.f};

#define ISSUE_W1(p) issue_w1(w1l + (size_t)(p) * 36864, \
                             w1l + (size_t)(p) * 36864 + 16 * 192, \
                             w1l + (size_t)(p) * 36864 + 32 * 192, \
                             b1l + (p) * 192, W1, BV)
#define ISSUE_W2(e, ch) issue_w2(w2l + (size_t)(e) * 73728 + (ch) * 48, \
                                 w2l + (size_t)(e) * 73728 + (ch) * 48 + 16 * 384, \
                                 w2l + (size_t)(e) * 73728 + (ch) * 48 + 32 * 384, W2)
#define LOAD_TOK(tk, e) do{ \
    _Pragma("unroll") \
    for (int np = 0; np < 4; ++np) tk[np] = lst[(e) * 64 + np * 16 + lq]; }while(0)

  // GEMM1 group np: gather X row by token id; 6kk x 3m MFMA
#define G1_NP(np, tk, hacc) do{ \
    const uint32_t xrow = OFF_X + tk[np] * XROWB; \
    _Pragma("unroll") \
    for (int kk = 0; kk < 6; ++kk){ \
      const u64 xk = *(const u64*)(S + xrow + (uint32_t)(kk * 32 + lg * 8)); \
      _Pragma("unroll") \
      for (int m = 0; m < 3; ++m){ \
        const u64 a = (kk & 1) ? W1[m * 3 + (kk >> 1)].y : W1[m * 3 + (kk >> 1)].x; \
        hacc[m][np] = mfma8(a, xk, hacc[m][np]); \
      } \
    } }while(0)
#define G1_COMP(ng, tk, hacc) do{ \
    _Pragma("unroll") \
    for (int m = 0; m < 3; ++m) \
      _Pragma("unroll") \
      for (int np = 0; np < 4; ++np) hacc[m][np] = BV[m]; \
    __builtin_amdgcn_s_setprio(1); \
    if (0 < (ng)) G1_NP(0, tk, hacc); \
    if (1 < (ng)) G1_NP(1, tk, hacc); \
    if (2 < (ng)) G1_NP(2, tk, hacc); \
    if (3 < (ng)) G1_NP(3, tk, hacc); \
    __builtin_amdgcn_s_setprio(0); }while(0)

  // GEMM2 group np: hid slot rows (compacted space)
#define G2_NP(np) do{ \
    _Pragma("unroll") \
    for (int kk = 0; kk < 6; ++kk){ \
      const u64 hf = *(const u64*)(S + rowh[np] + (uint32_t)(kk * 32 + lg * 8)); \
      _Pragma("unroll") \
      for (int m = 0; m < 3; ++m){ \
        const u64 a = (kk & 1) ? W2[m * 3 + (kk >> 1)].y : W2[m * 3 + (kk >> 1)].x; \
        oacc[m][np] = mfma8(a, hf, oacc[m][np]); \
      } \
    } }while(0)
#define G2_COMP(ng) do{ \
    __builtin_amdgcn_s_setprio(1); \
    if (0 < (ng)) G2_NP(0); \
    if (1 < (ng)) G2_NP(1); \
    if (2 < (ng)) G2_NP(2); \
    if (3 < (ng)) G2_NP(3); \
    __builtin_amdgcn_s_setprio(0); }while(0)

  // GELU*gate -> hid slot rows; pad slots (slot>=cnt) forced g=0 -> hid 0
#define GELU_ST(e, ng, ct, tk, hacc) do{ \
    _Pragma("unroll") \
    for (int np = 0; np < 4; ++np){ \
      if (np < (ng)){ \
        const float g = (np * 16 + lq < (ct)) ? gl[tk[np] * 4 + (e)] : 0.0f; \
        _Pragma("unroll") \
        for (int m = 0; m < 3; ++m){ \
          *(uint32_t*)(S + rowh[np] + (uint32_t)(48 * wv + 16 * m + 4 * lg)) = \
            fp8x4(gelu_f(hacc[m][np][0]) * g, gelu_f(hacc[m][np][1]) * g, \
                  gelu_f(hacc[m][np][2]) * g, gelu_f(hacc[m][np][3]) * g); \
        } \
      } \
    } }while(0)

  // scatter-add oacc into out LDS; pads -> dump row 64; reset oacc
#define SCATTER(e, ng, ct, tk) do{ \
    _Pragma("unroll") \
    for (int np = 0; np < 4; ++np){ \
      if (np < (ng)){ \
        const uint32_t srow = (np * 16 + lq < (ct)) ? tk[np] : 64u; \
        _Pragma("unroll") \
        for (int m = 0; m < 3; ++m){ \
          float* p = (float*)(S + OFF_OUT + srow * OROWB \
                              + (uint32_t)((48 * wv + 16 * m + 4 * lg) * 4)); \
          f32x4 c = *(const f32x4*)p; \
          c += oacc[m][np]; \
          *(f32x4*)p = c; \
        } \
      } \
      _Pragma("unroll") \
      for (int m = 0; m < 3; ++m) oacc[m][np] = (f32x4){0.f, 0.f, 0.f, 0.f}; \
    } }while(0)

  // ---- prologue: issue, zero out-accum (overlaps load latency), G1(0)->gelu->hid
  ISSUE_W1(0);
  ISSUE_W2(0, 0);
  {
    f32x4* oz = (f32x4*)(S + OFF_OUT);
    for (int i = tid; i < 65 * 49; i += 256) oz[i] = (f32x4){0.f, 0.f, 0.f, 0.f};
  }
  {
    const int ng = __builtin_amdgcn_readfirstlane(cw[0]);
    const int ct = __builtin_amdgcn_readfirstlane(cw[4]);
    uint32_t tk[4];
    LOAD_TOK(tk, 0);
    WAITV(9);                 // W1(0)+bias done; W2(0):9 outstanding
    f32x4 hacc[3][4];
    G1_COMP(ng, tk, hacc);
    GELU_ST(0, ng, ct, tk, hacc);
    ISSUE_W1(1);              // 9+12 = 21 in flight
  }
  BARRIER();                  // hid(0) + zero-fill visible

  // ---- main loop i=0..6
  #pragma unroll 1
  for (int i = 0; i < 7; ++i){
    const int e2 = i >> 1;
    const int p1 = i + 1, e1 = p1 >> 1, ch1 = p1 & 1;
    WAITV(12);                // W2(i) done; W1(i+1):12 outstanding
    {
      const int ng2 = __builtin_amdgcn_readfirstlane(cw[e2]);
      G2_COMP(ng2);
      if (i & 1){             // expert e2 finished: scatter + reset
        const int ct2 = __builtin_amdgcn_readfirstlane(cw[4 + e2]);
        uint32_t tk2[4];
        LOAD_TOK(tk2, e2);
        SCATTER(e2, ng2, ct2, tk2);
      }
    }
    ISSUE_W2(e1, ch1);        // 12+9 = 21
    WAITV(9);                 // W1(i+1)+bias done; W2(i+1):9 outstanding
    {
      const int ng1 = __builtin_amdgcn_readfirstlane(cw[e1]);
      const int ct1 = __builtin_amdgcn_readfirstlane(cw[4 + e1]);
      uint32_t tk1[4];
      LOAD_TOK(tk1, e1);
      f32x4 hacc[3][4];
      G1_COMP(ng1, tk1, hacc);
      BARRIER();              // all waves done reading hid_i
      GELU_ST(e1, ng1, ct1, tk1, hacc);
    }
    if (i < 6) ISSUE_W1(i + 2);   // 9+12 = 21
    BARRIER();                // hid_{i+1} visible
  }

  // ---- tail: G2(7) + scatter expert 3
  WAITV(0);
  {
    const int ng = __builtin_amdgcn_readfirstlane(cw[3]);
    const int ct = __builtin_amdgcn_readfirstlane(cw[4 + 3]);
    G2_COMP(ng);
    uint32_t tk[4];
    LOAD_TOK(tk, 3);
    SCATTER(3, ng, ct, tk);
  }
  BARRIER();                  // all scatters visible

  // ---- epilogue: coalesced read of out LDS + bias + residual + store
  {
    const int t = lane;
    const float sc = scp[0];
    const f32x4 g4 = *(const f32x4*)(S + OFF_GATE + t * 16);
    const float* xbt = xb + n0 + t;
    float* ob = out + (size_t)b * CC * NN + n0 + t;
    #pragma unroll
    for (int j = 0; j < 12; ++j){
      const int c0 = wv * 48 + j * 4;
      const f32x4 v = *(const f32x4*)(S + OFF_OUT + (uint32_t)t * OROWB + c0 * 4);
      #pragma unroll
      for (int r = 0; r < 4; ++r){
        const int c = c0 + r;
        const float bt = __builtin_fmaf(g4[0], b2[c],
                          __builtin_fmaf(g4[1], b2[CC + c],
                           __builtin_fmaf(g4[2], b2[2 * CC + c], g4[3] * b2[3 * CC + c])));
        ob[(size_t)c * NN] = __builtin_fmaf(sc, v[r] + bt, xbt[(size_t)c * NN]);
      }
    }
  }
#undef ISSUE_W1
#undef ISSUE_W2
#undef LOAD_TOK
#undef G1_NP
#undef G1_COMP
#undef G2_NP
#undef G2_COMP
#undef GELU_ST
#undef SCATTER
}

extern "C" void kernel_launch(void* const* d_in, const int* in_sizes, int n_in,
                              void* d_out, int out_size, void* d_ws, size_t ws_size,
                              hipStream_t stream){
  const float* x  = (const float*)d_in[0];
  const float* rw = (const float*)d_in[1];
  const float* rb = (const float*)d_in[2];
  const float* w1 = (const float*)d_in[3];
  const float* b1 = (const float*)d_in[4];
  const float* w2 = (const float*)d_in[5];
  const float* b2 = (const float*)d_in[6];
  const float* sc = (const float*)d_in[7];
  float* out = (float*)d_out;
  uint8_t* w1f8 = (uint8_t*)d_ws;
  uint8_t* w2f8 = w1f8 + 294912;

  hipLaunchKernelGGL(kconv, dim3(1152), dim3(256), 0, stream, w1, w2, w1f8, w2f8);
  hipLaunchKernelGGL(kmoe,  dim3(2048), dim3(256), 0, stream,
                     x, rw, rb, w1f8, b1, w2f8, b2, sc, out);
}

// Round 16
// 179.526 us; speedup vs baseline: 1.0589x; 1.0589x over previous
//
#include <hip/hip_runtime.h>
#include <stdint.h>

typedef __attribute__((ext_vector_type(4))) float f32x4;
typedef unsigned long long u64;
typedef __attribute__((ext_vector_type(2))) u64 u64x2;

#define CC   192
#define NN   16384
#define EE   4
#define HIDD 384

// LDS map (static, 65968 B -> 2 blocks/CU):
//  [0,     12800)  X tile [64 tok][200B] fp8 — resident whole kernel
//  [12800, 25600)  hid buf0 [64 slot][200B] fp8 (router partials pre-loop)
//  [25600, 38400)  hid buf1
//  [38400, 63880)  out accumulator bf16 [65 rows][392B] (row 64 = pad dump)
//  [63888, 64912)  gates [64 tok][4 e] f32
//  [64912, 65936)  lists u32 [4 e][64 slot]
//  [65936, 65968)  ng[4] @ +0, cnt[4] @ +16
// Round 16 = R15's compaction with R14's register lifetimes: double-buffered
// hid (GELU -> other buffer BEFORE the barrier, so hacc dies pre-barrier; R15's
// single-buffer forced hacc live across barrier+scatter -> 31MB scratch spill)
// and a bf16 out-accumulator (halves the LDS bill that forced single-buffer).
#define OFF_X    0u
#define OFF_H0   12800u
#define OFF_H1   25600u
#define OFF_PART 12800u
#define OFF_OUT  38400u
#define OFF_GATE 63888u
#define OFF_LIST 64912u
#define OFF_CNT  65936u
#define LDS_SZ   65968
#define XROWB    200u
#define OROWB    392u

// ---- fp8 e4m3fn convert
__device__ __forceinline__ uint32_t fp8b(float f){
  uint32_t u = __builtin_bit_cast(uint32_t, f);
  uint32_t s = (u >> 24) & 0x80u;
  float af = fminf(__builtin_fabsf(f), 448.0f);
  if (af < 0.015625f) return s;
  uint32_t v = __builtin_bit_cast(uint32_t, af);
  v += 0x7FFFFu + ((v >> 20) & 1u);
  uint32_t e = (v >> 23) - 120u;
  return s | (e << 3) | ((v >> 20) & 7u);
}
#if __has_builtin(__builtin_amdgcn_cvt_pk_fp8_f32)
__device__ __forceinline__ uint32_t fp8x4(float a, float b, float c, float d){
  int v = __builtin_amdgcn_cvt_pk_fp8_f32(a, b, 0, false);
  v = __builtin_amdgcn_cvt_pk_fp8_f32(c, d, v, true);
  return (uint32_t)v;
}
#else
__device__ __forceinline__ uint32_t fp8x4(float a, float b, float c, float d){
  return fp8b(a) | (fp8b(b) << 8) | (fp8b(c) << 16) | (fp8b(d) << 24);
}
#endif
// bf16 pack (RNE): low half = bf16(lo), high half = bf16(hi)
__device__ __forceinline__ uint32_t pkbf(float lo, float hi){
  uint32_t ul = __builtin_bit_cast(uint32_t, lo);
  uint32_t uh = __builtin_bit_cast(uint32_t, hi);
  ul += 0x7FFFu + ((ul >> 16) & 1u);
  uh += 0x7FFFu + ((uh >> 16) & 1u);
  return (ul >> 16) | (uh & 0xFFFF0000u);
}
__device__ __forceinline__ float upbf_lo(uint32_t u){
  return __builtin_bit_cast(float, u << 16);
}
__device__ __forceinline__ float upbf_hi(uint32_t u){
  return __builtin_bit_cast(float, u & 0xFFFF0000u);
}
// sigmoid-form GELU (R14-proven: absmax 0.046875)
__device__ __forceinline__ float gelu_f(float v){
  float e = __builtin_amdgcn_exp2f(v * -2.4554669f);
  return v * __builtin_amdgcn_rcpf(1.0f + e);
}
__device__ __forceinline__ f32x4 mfma8(u64 a, u64 b, f32x4 c){
  asm("v_mfma_f32_16x16x32_fp8_fp8 %0, %1, %2, %0" : "+v"(c) : "v"(a), "v"(b));
  return c;
}

#define WAITV(n) do{ asm volatile("s_waitcnt vmcnt(" #n ")"); \
                     __builtin_amdgcn_sched_barrier(0); }while(0)
#define BARRIER() do{ __builtin_amdgcn_sched_barrier(0); \
                      asm volatile("s_waitcnt lgkmcnt(0)"); \
                      __builtin_amdgcn_s_barrier(); \
                      __builtin_amdgcn_sched_barrier(0); }while(0)

// issue-only: 9 weight dwordx4 + 3 bias f32x4 (12 in flight)
__device__ __forceinline__ void issue_w1(const uint8_t* a0, const uint8_t* a1,
                                         const uint8_t* a2, const float* bb,
                                         u64x2 (&w)[9], f32x4 (&bv)[3]){
  asm volatile(
    "global_load_dwordx4 %0, %[A0], off\n\t"
    "global_load_dwordx4 %1, %[A0], off offset:16\n\t"
    "global_load_dwordx4 %2, %[A0], off offset:32\n\t"
    "global_load_dwordx4 %3, %[A1], off\n\t"
    "global_load_dwordx4 %4, %[A1], off offset:16\n\t"
    "global_load_dwordx4 %5, %[A1], off offset:32\n\t"
    "global_load_dwordx4 %6, %[A2], off\n\t"
    "global_load_dwordx4 %7, %[A2], off offset:16\n\t"
    "global_load_dwordx4 %8, %[A2], off offset:32\n\t"
    "global_load_dwordx4 %9, %[B], off\n\t"
    "global_load_dwordx4 %10, %[B], off offset:64\n\t"
    "global_load_dwordx4 %11, %[B], off offset:128"
    : "=&v"(w[0]), "=&v"(w[1]), "=&v"(w[2]), "=&v"(w[3]), "=&v"(w[4]), "=&v"(w[5]),
      "=&v"(w[6]), "=&v"(w[7]), "=&v"(w[8]), "=&v"(bv[0]), "=&v"(bv[1]), "=&v"(bv[2])
    : [A0]"v"(a0), [A1]"v"(a1), [A2]"v"(a2), [B]"v"(bb));
}
__device__ __forceinline__ void issue_w2(const uint8_t* a0, const uint8_t* a1,
                                         const uint8_t* a2, u64x2 (&w)[9]){
  asm volatile(
    "global_load_dwordx4 %0, %[A0], off\n\t"
    "global_load_dwordx4 %1, %[A0], off offset:16\n\t"
    "global_load_dwordx4 %2, %[A0], off offset:32\n\t"
    "global_load_dwordx4 %3, %[A1], off\n\t"
    "global_load_dwordx4 %4, %[A1], off offset:16\n\t"
    "global_load_dwordx4 %5, %[A1], off offset:32\n\t"
    "global_load_dwordx4 %6, %[A2], off\n\t"
    "global_load_dwordx4 %7, %[A2], off offset:16\n\t"
    "global_load_dwordx4 %8, %[A2], off offset:32"
    : "=&v"(w[0]), "=&v"(w[1]), "=&v"(w[2]), "=&v"(w[3]), "=&v"(w[4]), "=&v"(w[5]),
      "=&v"(w[6]), "=&v"(w[7]), "=&v"(w[8])
    : [A0]"v"(a0), [A1]"v"(a1), [A2]"v"(a2));
}

// weight convert + permute (unchanged from R13/R14/R15)
extern "C" __global__ void kconv(const float* __restrict__ w1, const float* __restrict__ w2,
                                 uint8_t* __restrict__ w1f8, uint8_t* __restrict__ w2f8){
  int i = blockIdx.x * 256 + threadIdx.x;
  {
    int row = i / 192, k = i % 192;
    int o = k >> 3, kk = o >> 2, lg = o & 3, bi = k & 7;
    w1f8[(size_t)row * 192 + lg * 48 + kk * 8 + bi] = (uint8_t)fp8b(w1[i]);
  }
  {
    int row = i / 384, k = i % 384;
    int o = k >> 3, kk = o >> 2, lg = o & 3, bi = k & 7;
    w2f8[(size_t)row * 384 + lg * 96 + kk * 8 + bi] = (uint8_t)fp8b(w2[i]);
  }
}

__global__ __launch_bounds__(256)
__attribute__((amdgpu_waves_per_eu(2, 2)))
void kmoe(const float* __restrict__ x, const float* __restrict__ rw,
          const float* __restrict__ rb, const uint8_t* __restrict__ w1f8,
          const float* __restrict__ b1, const uint8_t* __restrict__ w2f8,
          const float* __restrict__ b2, const float* __restrict__ scp,
          float* __restrict__ out)
{
  __shared__ __align__(16) unsigned char S[LDS_SZ];
  const int tid  = threadIdx.x;
  const int lane = tid & 63;
  const int wv   = tid >> 6;
  const int lq   = lane & 15;
  const int lg   = lane >> 4;
  const int tile = blockIdx.x;
  const int b    = tile >> 8;
  const int n0   = (tile & 255) << 6;
  const float* xb = x + (size_t)b * CC * NN;

  // ---- stage X (fp8, stride-200 rows) + fp32 router partials
  {
    const int t = lane;
    const uint32_t rowbase = (uint32_t)t * XROWB;
    float a0 = 0.f, a1 = 0.f, a2 = 0.f, a3 = 0.f;
    #pragma unroll
    for (int jj = 0; jj < 6; ++jj){
      float v[8];
      #pragma unroll
      for (int j = 0; j < 8; ++j){
        const int c = wv * 48 + jj * 8 + j;
        v[j] = xb[(size_t)c * NN + n0 + t];
        a0 = __builtin_fmaf(v[j], rw[c],          a0);
        a1 = __builtin_fmaf(v[j], rw[CC + c],     a1);
        a2 = __builtin_fmaf(v[j], rw[2 * CC + c], a2);
        a3 = __builtin_fmaf(v[j], rw[3 * CC + c], a3);
      }
      uint2 p;
      p.x = fp8x4(v[0], v[1], v[2], v[3]);
      p.y = fp8x4(v[4], v[5], v[6], v[7]);
      *(uint2*)(S + rowbase + (uint32_t)(wv * 48 + jj * 8)) = p;
    }
    float* pl = (float*)(S + OFF_PART);
    pl[(wv * 4 + 0) * 64 + t] = a0;
    pl[(wv * 4 + 1) * 64 + t] = a1;
    pl[(wv * 4 + 2) * 64 + t] = a2;
    pl[(wv * 4 + 3) * 64 + t] = a3;
  }
  __syncthreads();

  // ---- router finalize + compaction (wave 0)
  if (tid < 64){
    const int t = tid;
    const float* pl = (const float*)(S + OFF_PART);
    float l0 = rb[0], l1 = rb[1], l2 = rb[2], l3 = rb[3];
    #pragma unroll
    for (int cg = 0; cg < 4; ++cg){
      l0 += pl[(cg * 4 + 0) * 64 + t];
      l1 += pl[(cg * 4 + 1) * 64 + t];
      l2 += pl[(cg * 4 + 2) * 64 + t];
      l3 += pl[(cg * 4 + 3) * 64 + t];
    }
    int i1 = 0; float v1 = l0;
    if (l1 > v1){ v1 = l1; i1 = 1; }
    if (l2 > v1){ v1 = l2; i1 = 2; }
    if (l3 > v1){ v1 = l3; i1 = 3; }
    float v2 = -3.0e38f; int i2 = 0;
    if (i1 != 0){ v2 = l0; i2 = 0; }
    if (i1 != 1 && l1 > v2){ v2 = l1; i2 = 1; }
    if (i1 != 2 && l2 > v2){ v2 = l2; i2 = 2; }
    if (i1 != 3 && l3 > v2){ v2 = l3; i2 = 3; }
    const float ex = __expf(v2 - v1);
    const float ga = 1.0f / (1.0f + ex);
    const float gb = ex * ga;
    float* glw = (float*)(S + OFF_GATE);
    glw[t * 4 + 0] = (i1 == 0) ? ga : ((i2 == 0) ? gb : 0.0f);
    glw[t * 4 + 1] = (i1 == 1) ? ga : ((i2 == 1) ? gb : 0.0f);
    glw[t * 4 + 2] = (i1 == 2) ? ga : ((i2 == 2) ? gb : 0.0f);
    glw[t * 4 + 3] = (i1 == 3) ? ga : ((i2 == 3) ? gb : 0.0f);
    uint32_t* lst = (uint32_t*)(S + OFF_LIST);
    uint32_t* cw  = (uint32_t*)(S + OFF_CNT);
    #pragma unroll
    for (int e = 0; e < 4; ++e){
      const bool mine = (i1 == e) || (i2 == e);
      const u64 msk = __ballot(mine);
      const int cnt = __popcll(msk);
      const int ng  = (cnt + 15) >> 4;
      if (mine){
        const int slot = (int)__popcll(msk & ((1ull << t) - 1ull));
        lst[e * 64 + slot] = (uint32_t)t;
      }
      if (t >= cnt && t < ng * 16) lst[e * 64 + t] = 0u;
      if (t == 0){ cw[e] = (uint32_t)ng; cw[4 + e] = (uint32_t)cnt; }
    }
  }
  __syncthreads();   // X, gates, lists, counts settled

  const float* gl = (const float*)(S + OFF_GATE);
  const uint32_t* lst = (const uint32_t*)(S + OFF_LIST);
  const int* cw = (const int*)(S + OFF_CNT);
  uint32_t rowh[4];
  #pragma unroll
  for (int np = 0; np < 4; ++np) rowh[np] = (uint32_t)(16 * np + lq) * XROWB;

  const uint8_t* w1l = w1f8 + (size_t)(wv * 48 + lq) * 192 + lg * 48;
  const uint8_t* w2l = w2f8 + (size_t)(wv * 48 + lq) * 384 + lg * 96;
  const float*   b1l = b1 + wv * 48 + 4 * lg;

  u64x2 W1[9], W2[9];
  f32x4 BV[3];
  f32x4 oacc[3][4];
  #pragma unroll
  for (int m = 0; m < 3; ++m)
    #pragma unroll
    for (int np = 0; np < 4; ++np)
      oacc[m][np] = (f32x4){0.f, 0.f, 0.f, 0.f};

#define ISSUE_W1(p) issue_w1(w1l + (size_t)(p) * 36864, \
                             w1l + (size_t)(p) * 36864 + 16 * 192, \
                             w1l + (size_t)(p) * 36864 + 32 * 192, \
                             b1l + (p) * 192, W1, BV)
#define ISSUE_W2(e, ch) issue_w2(w2l + (size_t)(e) * 73728 + (ch) * 48, \
                                 w2l + (size_t)(e) * 73728 + (ch) * 48 + 16 * 384, \
                                 w2l + (size_t)(e) * 73728 + (ch) * 48 + 32 * 384, W2)
#define LOAD_TOK(tk, e) do{ \
    _Pragma("unroll") \
    for (int np = 0; np < 4; ++np) tk[np] = lst[(e) * 64 + np * 16 + lq]; }while(0)

#define G1_NP(np, tk, hacc) do{ \
    const uint32_t xrow = OFF_X + tk[np] * XROWB; \
    _Pragma("unroll") \
    for (int kk = 0; kk < 6; ++kk){ \
      const u64 xk = *(const u64*)(S + xrow + (uint32_t)(kk * 32 + lg * 8)); \
      _Pragma("unroll") \
      for (int m = 0; m < 3; ++m){ \
        const u64 a = (kk & 1) ? W1[m * 3 + (kk >> 1)].y : W1[m * 3 + (kk >> 1)].x; \
        hacc[m][np] = mfma8(a, xk, hacc[m][np]); \
      } \
    } }while(0)
#define G1_COMP(ng, tk, hacc) do{ \
    _Pragma("unroll") \
    for (int m = 0; m < 3; ++m) \
      _Pragma("unroll") \
      for (int np = 0; np < 4; ++np) hacc[m][np] = BV[m]; \
    __builtin_amdgcn_s_setprio(1); \
    if (0 < (ng)) G1_NP(0, tk, hacc); \
    if (1 < (ng)) G1_NP(1, tk, hacc); \
    if (2 < (ng)) G1_NP(2, tk, hacc); \
    if (3 < (ng)) G1_NP(3, tk, hacc); \
    __builtin_amdgcn_s_setprio(0); }while(0)

#define G2_NP(hb, np) do{ \
    _Pragma("unroll") \
    for (int kk = 0; kk < 6; ++kk){ \
      const u64 hf = *(const u64*)(S + (hb) + rowh[np] + (uint32_t)(kk * 32 + lg * 8)); \
      _Pragma("unroll") \
      for (int m = 0; m < 3; ++m){ \
        const u64 a = (kk & 1) ? W2[m * 3 + (kk >> 1)].y : W2[m * 3 + (kk >> 1)].x; \
        oacc[m][np] = mfma8(a, hf, oacc[m][np]); \
      } \
    } }while(0)
#define G2_COMP(hb, ng) do{ \
    __builtin_amdgcn_s_setprio(1); \
    if (0 < (ng)) G2_NP(hb, 0); \
    if (1 < (ng)) G2_NP(hb, 1); \
    if (2 < (ng)) G2_NP(hb, 2); \
    if (3 < (ng)) G2_NP(hb, 3); \
    __builtin_amdgcn_s_setprio(0); }while(0)

  // GELU*gate -> hid buffer hb (slot rows); pad slots g=0 -> hid 0
#define GELU_ST(hb, e, ng, ct, tk, hacc) do{ \
    _Pragma("unroll") \
    for (int np = 0; np < 4; ++np){ \
      if (np < (ng)){ \
        const float g = (np * 16 + lq < (ct)) ? gl[tk[np] * 4 + (e)] : 0.0f; \
        _Pragma("unroll") \
        for (int m = 0; m < 3; ++m){ \
          *(uint32_t*)(S + (hb) + rowh[np] + (uint32_t)(48 * wv + 16 * m + 4 * lg)) = \
            fp8x4(gelu_f(hacc[m][np][0]) * g, gelu_f(hacc[m][np][1]) * g, \
                  gelu_f(hacc[m][np][2]) * g, gelu_f(hacc[m][np][3]) * g); \
        } \
      } \
    } }while(0)

  // scatter-add oacc into bf16 out rows; pads -> dump row 64; reset oacc
#define SCATTER(ng, ct, tk) do{ \
    _Pragma("unroll") \
    for (int np = 0; np < 4; ++np){ \
      if (np < (ng)){ \
        const uint32_t srow = (np * 16 + lq < (ct)) ? tk[np] : 64u; \
        _Pragma("unroll") \
        for (int m = 0; m < 3; ++m){ \
          uint32_t* p = (uint32_t*)(S + OFF_OUT + srow * OROWB \
                                    + (uint32_t)((48 * wv + 16 * m + 4 * lg) * 2)); \
          uint2 c = *(const uint2*)p; \
          const float c0 = upbf_lo(c.x) + oacc[m][np][0]; \
          const float c1 = upbf_hi(c.x) + oacc[m][np][1]; \
          const float c2 = upbf_lo(c.y) + oacc[m][np][2]; \
          const float c3 = upbf_hi(c.y) + oacc[m][np][3]; \
          c.x = pkbf(c0, c1); c.y = pkbf(c2, c3); \
          *(uint2*)p = c; \
        } \
      } \
      _Pragma("unroll") \
      for (int m = 0; m < 3; ++m) oacc[m][np] = (f32x4){0.f, 0.f, 0.f, 0.f}; \
    } }while(0)

  // ---- prologue: issue, zero out-accum (under load latency), G1(0)->gelu->H0
  ISSUE_W1(0);
  ISSUE_W2(0, 0);
  {
    uint2* oz = (uint2*)(S + OFF_OUT);
    for (int i = tid; i < 65 * 49; i += 256) oz[i] = (uint2){0u, 0u};
  }
  {
    const int ng = __builtin_amdgcn_readfirstlane(cw[0]);
    const int ct = __builtin_amdgcn_readfirstlane(cw[4]);
    uint32_t tk[4];
    LOAD_TOK(tk, 0);
    WAITV(9);                 // W1(0)+bias done; W2(0):9 outstanding
    f32x4 hacc[3][4];
    G1_COMP(ng, tk, hacc);
    GELU_ST(OFF_H0, 0, ng, ct, tk, hacc);
    ISSUE_W1(1);              // 9+12 = 21 in flight
  }
  BARRIER();                  // hid(0) + zero-fill visible

  // ---- main loop i=0..6: G2_i(hb_r) [+scatter] ; G1_{i+1}->gelu->hb_w ; barrier
  #pragma unroll 1
  for (int i = 0; i < 7; ++i){
    const uint32_t hb_r = (i & 1) ? OFF_H1 : OFF_H0;
    const uint32_t hb_w = (i & 1) ? OFF_H0 : OFF_H1;
    const int e2 = i >> 1;
    const int p1 = i + 1, e1 = p1 >> 1, ch1 = p1 & 1;
    WAITV(12);                // W2(i) done; W1(i+1):12 outstanding
    {
      const int ng2 = __builtin_amdgcn_readfirstlane(cw[e2]);
      G2_COMP(hb_r, ng2);
      if (i & 1){             // expert e2 complete -> scatter + reset oacc
        const int ct2 = __builtin_amdgcn_readfirstlane(cw[4 + e2]);
        uint32_t tk2[4];
        LOAD_TOK(tk2, e2);
        SCATTER(ng2, ct2, tk2);
      }
    }
    ISSUE_W2(e1, ch1);        // 12+9 = 21
    WAITV(9);                 // W1(i+1)+bias done; W2(i+1):9 outstanding
    {
      const int ng1 = __builtin_amdgcn_readfirstlane(cw[e1]);
      const int ct1 = __builtin_amdgcn_readfirstlane(cw[4 + e1]);
      uint32_t tk1[4];
      LOAD_TOK(tk1, e1);
      f32x4 hacc[3][4];
      G1_COMP(ng1, tk1, hacc);
      GELU_ST(hb_w, e1, ng1, ct1, tk1, hacc);   // other buffer, pre-barrier
    }
    if (i < 6) ISSUE_W1(i + 2);   // 9+12 = 21
    BARRIER();                // hid_{i+1} visible; hb_r reads all complete
  }

  // ---- tail: G2(7) reads H1 (written at i=6) + scatter expert 3
  WAITV(0);
  {
    const int ng = __builtin_amdgcn_readfirstlane(cw[3]);
    const int ct = __builtin_amdgcn_readfirstlane(cw[4 + 3]);
    G2_COMP(OFF_H1, ng);
    uint32_t tk[4];
    LOAD_TOK(tk, 3);
    SCATTER(ng, ct, tk);
  }
  BARRIER();                  // all scatters visible

  // ---- epilogue: coalesced bf16 out read + bias + residual + store
  {
    const int t = lane;
    const float sc = scp[0];
    const f32x4 g4 = *(const f32x4*)(S + OFF_GATE + t * 16);
    const float* xbt = xb + n0 + t;
    float* ob = out + (size_t)b * CC * NN + n0 + t;
    #pragma unroll
    for (int j = 0; j < 12; ++j){
      const int c0 = wv * 48 + j * 4;
      const uint2 pv = *(const uint2*)(S + OFF_OUT + (uint32_t)t * OROWB
                                       + (uint32_t)(c0 * 2));
      float v[4];
      v[0] = upbf_lo(pv.x); v[1] = upbf_hi(pv.x);
      v[2] = upbf_lo(pv.y); v[3] = upbf_hi(pv.y);
      #pragma unroll
      for (int r = 0; r < 4; ++r){
        const int c = c0 + r;
        const float bt = __builtin_fmaf(g4[0], b2[c],
                          __builtin_fmaf(g4[1], b2[CC + c],
                           __builtin_fmaf(g4[2], b2[2 * CC + c], g4[3] * b2[3 * CC + c])));
        ob[(size_t)c * NN] = __builtin_fmaf(sc, v[r] + bt, xbt[(size_t)c * NN]);
      }
    }
  }
#undef ISSUE_W1
#undef ISSUE_W2
#undef LOAD_TOK
#undef G1_NP
#undef G1_COMP
#undef G2_NP
#undef G2_COMP
#undef GELU_ST
#undef SCATTER
}

extern "C" void kernel_launch(void* const* d_in, const int* in_sizes, int n_in,
                              void* d_out, int out_size, void* d_ws, size_t ws_size,
                              hipStream_t stream){
  const float* x  = (const float*)d_in[0];
  const float* rw = (const float*)d_in[1];
  const float* rb = (const float*)d_in[2];
  const float* w1 = (const float*)d_in[3];
  const float* b1 = (const float*)d_in[4];
  const float* w2 = (const float*)d_in[5];
  const float* b2 = (const float*)d_in[6];
  const float* sc = (const float*)d_in[7];
  float* out = (float*)d_out;
  uint8_t* w1f8 = (uint8_t*)d_ws;
  uint8_t* w2f8 = w1f8 + 294912;

  hipLaunchKernelGGL(kconv, dim3(1152), dim3(256), 0, stream, w1, w2, w1f8, w2f8);
  hipLaunchKernelGGL(kmoe,  dim3(2048), dim3(256), 0, stream,
                     x, rw, rb, w1f8, b1, w2f8, b2, sc, out);
}

// Round 17
// 166.576 us; speedup vs baseline: 1.1412x; 1.0777x over previous
//
#include <hip/hip_runtime.h>
#include <stdint.h>

typedef __attribute__((ext_vector_type(4))) float f32x4;
typedef unsigned long long u64;
typedef __attribute__((ext_vector_type(2))) u64 u64x2;

#define CC   192
#define NN   16384
#define EE   4
#define HIDD 384

// LDS map (static, 39424 B), rows padded to 200 B (50 words; 50%32=18,
// gcd(18,32)=2 -> 18*lq covers all 16 even banks once for lq=0..15):
//  [0,     12800)  X tile [64 tok][200B] fp8 — resident whole kernel
//  [12800, 25600)  hid buf0 [64][200B] fp8 (router partials f32[16][64] pre-loop)
//  [25600, 38400)  hid buf1
//  [38400, 39424)  gates [64 tok][4 e] f32
// FINAL (= round 14, the series optimum: 166us headline / 199us profiled,
// absmax 0.047, zero spill). Series evidence:
//  - R12 ablation: weight DELIVERY was 63% of runtime -> R13's asm-held
//    counted-vmcnt prefetch pipeline (21 loads in flight, raw s_barrier,
//    never vmcnt(0) in-loop) + all-fp8 = 378->210us.
//  - R14: stride-200 LDS (conflicts 14.5M->524K) + sigmoid GELU = 210->199.
//  - R15/R16: top-2 compaction cuts MFMA 66->39us but ALWAYS spills
//    (register budget at 2 waves/EU is intrinsically exceeded) -> reverted.
//  - Occupancy is register-locked at 2 waves/SIMD: R3/R7/R15/R16 all spilled
//    when pushed. MfmaUtil 33% + VALUBusy 43% = 76% combined; floor ~ max(75
//    MFMA, 86 VALU)us; remaining stall is barrier sync at 2-deep occupancy.
#define OFF_H0   12800u
#define OFF_H1   25600u
#define OFF_PART 12800
#define OFF_GATE 38400
#define LDS_SZ   39424
#define ROWS     200u

// ---- fp8 e4m3fn convert
__device__ __forceinline__ uint32_t fp8b(float f){
  uint32_t u = __builtin_bit_cast(uint32_t, f);
  uint32_t s = (u >> 24) & 0x80u;
  float af = fminf(__builtin_fabsf(f), 448.0f);
  if (af < 0.015625f) return s;                 // FTZ below normal range
  uint32_t v = __builtin_bit_cast(uint32_t, af);
  v += 0x7FFFFu + ((v >> 20) & 1u);             // RNE into 3-bit mantissa
  uint32_t e = (v >> 23) - 120u;                // bias 127 -> 7
  return s | (e << 3) | ((v >> 20) & 7u);
}
#if __has_builtin(__builtin_amdgcn_cvt_pk_fp8_f32)
__device__ __forceinline__ uint32_t fp8x4(float a, float b, float c, float d){
  int v = __builtin_amdgcn_cvt_pk_fp8_f32(a, b, 0, false);
  v = __builtin_amdgcn_cvt_pk_fp8_f32(c, d, v, true);
  return (uint32_t)v;
}
#else
__device__ __forceinline__ uint32_t fp8x4(float a, float b, float c, float d){
  return fp8b(a) | (fp8b(b) << 8) | (fp8b(c) << 16) | (fp8b(d) << 24);
}
#endif
// sigmoid-form GELU: x*sigma(1.702x). Measured absmax 0.046875 (thr 0.109).
__device__ __forceinline__ float gelu_f(float v){
  float e = __builtin_amdgcn_exp2f(v * -2.4554669f);   // exp2(-1.702*log2e*x)
  return v * __builtin_amdgcn_rcpf(1.0f + e);
}
// fp8 MFMA via asm (R8 hardware-proven path + layout)
__device__ __forceinline__ f32x4 mfma8(u64 a, u64 b, f32x4 c){
  asm("v_mfma_f32_16x16x32_fp8_fp8 %0, %1, %2, %0" : "+v"(c) : "v"(a), "v"(b));
  return c;
}

#define WAITV(n) do{ asm volatile("s_waitcnt vmcnt(" #n ")"); \
                     __builtin_amdgcn_sched_barrier(0); }while(0)
#define BARRIER() do{ __builtin_amdgcn_sched_barrier(0); \
                      asm volatile("s_waitcnt lgkmcnt(0)"); \
                      __builtin_amdgcn_s_barrier(); \
                      __builtin_amdgcn_sched_barrier(0); }while(0)

// issue-only: 9 weight dwordx4 (3 bases x offsets 0/16/32) + 3 bias f32x4
__device__ __forceinline__ void issue_w1(const uint8_t* a0, const uint8_t* a1,
                                         const uint8_t* a2, const float* bb,
                                         u64x2 (&w)[9], f32x4 (&bv)[3]){
  asm volatile(
    "global_load_dwordx4 %0, %[A0], off\n\t"
    "global_load_dwordx4 %1, %[A0], off offset:16\n\t"
    "global_load_dwordx4 %2, %[A0], off offset:32\n\t"
    "global_load_dwordx4 %3, %[A1], off\n\t"
    "global_load_dwordx4 %4, %[A1], off offset:16\n\t"
    "global_load_dwordx4 %5, %[A1], off offset:32\n\t"
    "global_load_dwordx4 %6, %[A2], off\n\t"
    "global_load_dwordx4 %7, %[A2], off offset:16\n\t"
    "global_load_dwordx4 %8, %[A2], off offset:32\n\t"
    "global_load_dwordx4 %9, %[B], off\n\t"
    "global_load_dwordx4 %10, %[B], off offset:64\n\t"
    "global_load_dwordx4 %11, %[B], off offset:128"
    : "=&v"(w[0]), "=&v"(w[1]), "=&v"(w[2]), "=&v"(w[3]), "=&v"(w[4]), "=&v"(w[5]),
      "=&v"(w[6]), "=&v"(w[7]), "=&v"(w[8]), "=&v"(bv[0]), "=&v"(bv[1]), "=&v"(bv[2])
    : [A0]"v"(a0), [A1]"v"(a1), [A2]"v"(a2), [B]"v"(bb));
}
__device__ __forceinline__ void issue_w2(const uint8_t* a0, const uint8_t* a1,
                                         const uint8_t* a2, u64x2 (&w)[9]){
  asm volatile(
    "global_load_dwordx4 %0, %[A0], off\n\t"
    "global_load_dwordx4 %1, %[A0], off offset:16\n\t"
    "global_load_dwordx4 %2, %[A0], off offset:32\n\t"
    "global_load_dwordx4 %3, %[A1], off\n\t"
    "global_load_dwordx4 %4, %[A1], off offset:16\n\t"
    "global_load_dwordx4 %5, %[A1], off offset:32\n\t"
    "global_load_dwordx4 %6, %[A2], off\n\t"
    "global_load_dwordx4 %7, %[A2], off offset:16\n\t"
    "global_load_dwordx4 %8, %[A2], off offset:32"
    : "=&v"(w[0]), "=&v"(w[1]), "=&v"(w[2]), "=&v"(w[3]), "=&v"(w[4]), "=&v"(w[5]),
      "=&v"(w[6]), "=&v"(w[7]), "=&v"(w[8])
    : [A0]"v"(a0), [A1]"v"(a1), [A2]"v"(a2));
}

// weight convert + permute: row-local layout [lg][kk][8B] so one dwordx4 at
// lg*(L/4) + j*16 delivers the frags for kk=2j, 2j+1 (frag k = kk*32+lg*8+b).
extern "C" __global__ void kconv(const float* __restrict__ w1, const float* __restrict__ w2,
                                 uint8_t* __restrict__ w1f8, uint8_t* __restrict__ w2f8){
  int i = blockIdx.x * 256 + threadIdx.x;
  {
    int row = i / 192, k = i % 192;
    int o = k >> 3, kk = o >> 2, lg = o & 3, bi = k & 7;
    w1f8[(size_t)row * 192 + lg * 48 + kk * 8 + bi] = (uint8_t)fp8b(w1[i]);
  }
  {
    int row = i / 384, k = i % 384;
    int o = k >> 3, kk = o >> 2, lg = o & 3, bi = k & 7;
    w2f8[(size_t)row * 384 + lg * 96 + kk * 8 + bi] = (uint8_t)fp8b(w2[i]);
  }
}

__global__ __launch_bounds__(256)
__attribute__((amdgpu_waves_per_eu(2, 2)))
void kmoe(const float* __restrict__ x, const float* __restrict__ rw,
          const float* __restrict__ rb, const uint8_t* __restrict__ w1f8,
          const float* __restrict__ b1, const uint8_t* __restrict__ w2f8,
          const float* __restrict__ b2, const float* __restrict__ scp,
          float* __restrict__ out)
{
  __shared__ __align__(16) unsigned char S[LDS_SZ];
  const int tid  = threadIdx.x;
  const int lane = tid & 63;
  const int wv   = tid >> 6;
  const int lq   = lane & 15;
  const int lg   = lane >> 4;
  const int tile = blockIdx.x;
  const int b    = tile >> 8;
  const int n0   = (tile & 255) << 6;
  const float* xb = x + (size_t)b * CC * NN;

  // ---- stage X (fp8, stride-200 rows, 8B writes) + fp32 router partials
  {
    const int t = lane;
    const uint32_t rowbase = (uint32_t)t * ROWS;
    float a0 = 0.f, a1 = 0.f, a2 = 0.f, a3 = 0.f;
    #pragma unroll
    for (int jj = 0; jj < 6; ++jj){
      float v[8];
      #pragma unroll
      for (int j = 0; j < 8; ++j){
        const int c = wv * 48 + jj * 8 + j;
        v[j] = xb[(size_t)c * NN + n0 + t];
        a0 = __builtin_fmaf(v[j], rw[c],          a0);
        a1 = __builtin_fmaf(v[j], rw[CC + c],     a1);
        a2 = __builtin_fmaf(v[j], rw[2 * CC + c], a2);
        a3 = __builtin_fmaf(v[j], rw[3 * CC + c], a3);
      }
      uint2 p;
      p.x = fp8x4(v[0], v[1], v[2], v[3]);
      p.y = fp8x4(v[4], v[5], v[6], v[7]);
      *(uint2*)(S + rowbase + (uint32_t)(wv * 48 + jj * 8)) = p;
    }
    float* pl = (float*)(S + OFF_PART);
    pl[(wv * 4 + 0) * 64 + t] = a0;
    pl[(wv * 4 + 1) * 64 + t] = a1;
    pl[(wv * 4 + 2) * 64 + t] = a2;
    pl[(wv * 4 + 3) * 64 + t] = a3;
  }
  __syncthreads();

  // ---- router finalize (fp32, top-2 tie->lower, softmax) -> gates
  if (tid < 64){
    const int t = tid;
    const float* pl = (const float*)(S + OFF_PART);
    float l0 = rb[0], l1 = rb[1], l2 = rb[2], l3 = rb[3];
    #pragma unroll
    for (int cg = 0; cg < 4; ++cg){
      l0 += pl[(cg * 4 + 0) * 64 + t];
      l1 += pl[(cg * 4 + 1) * 64 + t];
      l2 += pl[(cg * 4 + 2) * 64 + t];
      l3 += pl[(cg * 4 + 3) * 64 + t];
    }
    int i1 = 0; float v1 = l0;
    if (l1 > v1){ v1 = l1; i1 = 1; }
    if (l2 > v1){ v1 = l2; i1 = 2; }
    if (l3 > v1){ v1 = l3; i1 = 3; }
    float v2 = -3.0e38f; int i2 = 0;
    if (i1 != 0){ v2 = l0; i2 = 0; }
    if (i1 != 1 && l1 > v2){ v2 = l1; i2 = 1; }
    if (i1 != 2 && l2 > v2){ v2 = l2; i2 = 2; }
    if (i1 != 3 && l3 > v2){ v2 = l3; i2 = 3; }
    const float ex = __expf(v2 - v1);
    const float ga = 1.0f / (1.0f + ex);
    const float gb = ex * ga;
    float* glw = (float*)(S + OFF_GATE);
    glw[t * 4 + 0] = (i1 == 0) ? ga : ((i2 == 0) ? gb : 0.0f);
    glw[t * 4 + 1] = (i1 == 1) ? ga : ((i2 == 1) ? gb : 0.0f);
    glw[t * 4 + 2] = (i1 == 2) ? ga : ((i2 == 2) ? gb : 0.0f);
    glw[t * 4 + 3] = (i1 == 3) ? ga : ((i2 == 3) ? gb : 0.0f);
  }
  __syncthreads();   // full drain OK here: nothing prefetched yet

  const float* gl = (const float*)(S + OFF_GATE);
  uint32_t rowb[4];
  #pragma unroll
  for (int np = 0; np < 4; ++np) rowb[np] = (uint32_t)(16 * np + lq) * ROWS;

  // per-lane weight/bias bases (phase p: e=p>>1, ch=p&1)
  const uint8_t* w1l = w1f8 + (size_t)(wv * 48 + lq) * 192 + lg * 48;  // + p*36864
  const uint8_t* w2l = w2f8 + (size_t)(wv * 48 + lq) * 384 + lg * 96;  // + e*73728 + ch*48
  const float*   b1l = b1 + wv * 48 + 4 * lg;                          // + p*192 (+16m)

  u64x2 W1[9], W2[9];
  f32x4 BV[3];
  f32x4 oacc[3][4];
  #pragma unroll
  for (int m = 0; m < 3; ++m)
    #pragma unroll
    for (int np = 0; np < 4; ++np)
      oacc[m][np] = (f32x4){0.f, 0.f, 0.f, 0.f};

#define ISSUE_W1(p) issue_w1(w1l + (size_t)(p) * 36864, \
                             w1l + (size_t)(p) * 36864 + 16 * 192, \
                             w1l + (size_t)(p) * 36864 + 32 * 192, \
                             b1l + (p) * 192, W1, BV)
#define ISSUE_W2(e, ch) issue_w2(w2l + (size_t)(e) * 73728 + (ch) * 48, \
                                 w2l + (size_t)(e) * 73728 + (ch) * 48 + 16 * 384, \
                                 w2l + (size_t)(e) * 73728 + (ch) * 48 + 32 * 384, W2)

  // GEMM1 compute: A = w1 frags (regs), B = X (LDS fp8), bias-init
#define G1_COMP(hacc) do{ \
    _Pragma("unroll") \
    for (int m = 0; m < 3; ++m) \
      _Pragma("unroll") \
      for (int np = 0; np < 4; ++np) hacc[m][np] = BV[m]; \
    __builtin_amdgcn_s_setprio(1); \
    _Pragma("unroll") \
    for (int kk = 0; kk < 6; ++kk){ \
      u64 xk[4]; \
      _Pragma("unroll") \
      for (int np = 0; np < 4; ++np) \
        xk[np] = *(const u64*)(S + rowb[np] + (uint32_t)(kk * 32 + lg * 8)); \
      _Pragma("unroll") \
      for (int np = 0; np < 4; ++np) \
        _Pragma("unroll") \
        for (int m = 0; m < 3; ++m){ \
          const u64 a = (kk & 1) ? W1[m * 3 + (kk >> 1)].y : W1[m * 3 + (kk >> 1)].x; \
          hacc[m][np] = mfma8(a, xk[np], hacc[m][np]); \
        } \
    } \
    __builtin_amdgcn_s_setprio(0); }while(0)

#define G2_COMP(hb) do{ \
    __builtin_amdgcn_s_setprio(1); \
    _Pragma("unroll") \
    for (int kk = 0; kk < 6; ++kk){ \
      u64 hf[4]; \
      _Pragma("unroll") \
      for (int np = 0; np < 4; ++np) \
        hf[np] = *(const u64*)(S + (hb) + rowb[np] + (uint32_t)(kk * 32 + lg * 8)); \
      _Pragma("unroll") \
      for (int np = 0; np < 4; ++np) \
        _Pragma("unroll") \
        for (int m = 0; m < 3; ++m){ \
          const u64 a = (kk & 1) ? W2[m * 3 + (kk >> 1)].y : W2[m * 3 + (kk >> 1)].x; \
          oacc[m][np] = mfma8(a, hf[np], oacc[m][np]); \
        } \
    } \
    __builtin_amdgcn_s_setprio(0); }while(0)

#define GELU_ST(hb, e, hacc) do{ \
    _Pragma("unroll") \
    for (int np = 0; np < 4; ++np){ \
      const float g = gl[(16 * np + lq) * 4 + (e)]; \
      _Pragma("unroll") \
      for (int m = 0; m < 3; ++m){ \
        const uint32_t colb = (uint32_t)(48 * wv + 16 * m + 4 * lg); \
        *(uint32_t*)(S + (hb) + rowb[np] + colb) = \
          fp8x4(gelu_f(hacc[m][np][0]) * g, gelu_f(hacc[m][np][1]) * g, \
                gelu_f(hacc[m][np][2]) * g, gelu_f(hacc[m][np][3]) * g); \
      } \
    } }while(0)

  // ---- prologue: phase 0 G1 -> gelu -> H0 (pipeline fill: 21 loads in flight)
  {
    ISSUE_W1(0);
    ISSUE_W2(0, 0);
    WAITV(9);                 // W1(0)+bias done; W2(0):9 outstanding
    f32x4 hacc[3][4];
    G1_COMP(hacc);
    GELU_ST(OFF_H0, 0, hacc);
    ISSUE_W1(1);              // outstanding: W2(0):9 + W1(1):12 = 21
  }
  BARRIER();

  // ---- main loop i=0..6: G2(i) ; G1(i+1) ; gelu -> other buf ; raw barrier
  #pragma unroll 1
  for (int i = 0; i < 7; ++i){
    const uint32_t hb_r = (i & 1) ? OFF_H1 : OFF_H0;
    const uint32_t hb_w = (i & 1) ? OFF_H0 : OFF_H1;
    WAITV(12);                // W2(i) done; W1(i+1):12 outstanding
    G2_COMP(hb_r);
    {
      const int p = i + 1;
      ISSUE_W2(p >> 1, p & 1);   // 12+9 = 21
    }
    WAITV(9);                 // W1(i+1)+bias done; W2(i+1):9 outstanding
    f32x4 hacc[3][4];
    G1_COMP(hacc);
    GELU_ST(hb_w, (i + 1) >> 1, hacc);
    if (i < 6) ISSUE_W1(i + 2);   // 9+12 = 21
    BARRIER();
  }

  // ---- tail: G2(7) reads H1
  WAITV(0);
  G2_COMP(OFF_H1);

  // ---- epilogue: direct stores (64B segments, L2 write-combines to lines)
  {
    const float sc = scp[0];
    f32x4 g4v[4];
    #pragma unroll
    for (int np = 0; np < 4; ++np)
      g4v[np] = *(const f32x4*)(S + OFF_GATE + (16 * np + lq) * 16);
    const size_t obase = (size_t)b * CC * NN + n0;
    #pragma unroll
    for (int m = 0; m < 3; ++m){
      const int f0 = 48 * wv + 16 * m + 4 * lg;
      f32x4 b2q[4];
      #pragma unroll
      for (int e = 0; e < 4; ++e)
        b2q[e] = *(const f32x4*)(b2 + e * CC + f0);
      #pragma unroll
      for (int np = 0; np < 4; ++np){
        const int tok = 16 * np + lq;
        #pragma unroll
        for (int r = 0; r < 4; ++r){
          const float bt = __builtin_fmaf(g4v[np][0], b2q[0][r],
                            __builtin_fmaf(g4v[np][1], b2q[1][r],
                             __builtin_fmaf(g4v[np][2], b2q[2][r],
                                            g4v[np][3] * b2q[3][r])));
          const size_t off = obase + (size_t)(f0 + r) * NN + tok;
          out[off] = __builtin_fmaf(sc, oacc[m][np][r] + bt, x[off]);
        }
      }
    }
  }
#undef ISSUE_W1
#undef ISSUE_W2
#undef G1_COMP
#undef G2_COMP
#undef GELU_ST
}

extern "C" void kernel_launch(void* const* d_in, const int* in_sizes, int n_in,
                              void* d_out, int out_size, void* d_ws, size_t ws_size,
                              hipStream_t stream){
  const float* x  = (const float*)d_in[0];
  const float* rw = (const float*)d_in[1];
  const float* rb = (const float*)d_in[2];
  const float* w1 = (const float*)d_in[3];
  const float* b1 = (const float*)d_in[4];
  const float* w2 = (const float*)d_in[5];
  const float* b2 = (const float*)d_in[6];
  const float* sc = (const float*)d_in[7];
  float* out = (float*)d_out;
  uint8_t* w1f8 = (uint8_t*)d_ws;
  uint8_t* w2f8 = w1f8 + 294912;

  hipLaunchKernelGGL(kconv, dim3(1152), dim3(256), 0, stream, w1, w2, w1f8, w2f8);
  hipLaunchKernelGGL(kmoe,  dim3(2048), dim3(256), 0, stream,
                     x, rw, rb, w1f8, b1, w2f8, b2, sc, out);
}